// Round 1
// baseline (9642.988 us; speedup 1.0000x reference)
//
#include <hip/hip_runtime.h>
#include <math.h>

// Problem constants
#define B_ 4
#define T_ 2048
#define C_ 1024
#define H_ 16
#define D_ 64
// M = B*T = 8192, K = C = 1024, N1 = 3*C = 3072, N2 = C = 1024

// ---------------------------------------------------------------------------
// GEMM1: qkv = x @ w_qkv + b_qkv, scattered to q/k/v in [B,H,T,D] layout.
// 128x128 tile, BK=16, 256 threads, 8x8 per thread, fp32.
// ---------------------------------------------------------------------------
__global__ __launch_bounds__(256) void gemm_qkv(
    const float* __restrict__ A,    // x [8192,1024]
    const float* __restrict__ Bw,   // w_qkv [1024,3072]
    const float* __restrict__ bias, // [3072]
    float* __restrict__ qo, float* __restrict__ ko, float* __restrict__ vo)
{
    const int K = C_, N = 3 * C_;
    __shared__ __align__(16) float As[16][132]; // [k][m] transposed
    __shared__ __align__(16) float Bs[16][132]; // [k][n]
    const int tid = threadIdx.x;
    const int bm = blockIdx.y * 128, bn = blockIdx.x * 128;
    const int ty = tid >> 4, tx = tid & 15;

    float acc[8][8];
#pragma unroll
    for (int i = 0; i < 8; ++i)
#pragma unroll
        for (int j = 0; j < 8; ++j) acc[i][j] = 0.f;

    for (int k0 = 0; k0 < K; k0 += 16) {
        // A tile: 128 rows x 16 cols, 512 float4s
#pragma unroll
        for (int i = 0; i < 2; ++i) {
            int f = tid + 256 * i;
            int r = f >> 2, c = (f & 3) << 2;
            float4 av = *reinterpret_cast<const float4*>(&A[(size_t)(bm + r) * K + k0 + c]);
            As[c + 0][r] = av.x; As[c + 1][r] = av.y;
            As[c + 2][r] = av.z; As[c + 3][r] = av.w;
        }
        // B tile: 16 rows x 128 cols
#pragma unroll
        for (int i = 0; i < 2; ++i) {
            int f = tid + 256 * i;
            int r = f >> 5, c = (f & 31) << 2;
            float4 bv = *reinterpret_cast<const float4*>(&Bw[(size_t)(k0 + r) * N + bn + c]);
            Bs[r][c + 0] = bv.x; Bs[r][c + 1] = bv.y;
            Bs[r][c + 2] = bv.z; Bs[r][c + 3] = bv.w;
        }
        __syncthreads();
#pragma unroll
        for (int kk = 0; kk < 16; ++kk) {
            float a[8], b[8];
#pragma unroll
            for (int i = 0; i < 8; i += 4) {
                float4 t = *reinterpret_cast<const float4*>(&As[kk][ty * 8 + i]);
                a[i] = t.x; a[i + 1] = t.y; a[i + 2] = t.z; a[i + 3] = t.w;
            }
#pragma unroll
            for (int j = 0; j < 8; j += 4) {
                float4 t = *reinterpret_cast<const float4*>(&Bs[kk][tx * 8 + j]);
                b[j] = t.x; b[j + 1] = t.y; b[j + 2] = t.z; b[j + 3] = t.w;
            }
#pragma unroll
            for (int i = 0; i < 8; ++i)
#pragma unroll
                for (int j = 0; j < 8; ++j)
                    acc[i][j] = fmaf(a[i], b[j], acc[i][j]);
        }
        __syncthreads();
    }

    // epilogue: scatter to q/k/v [B,H,T,D] with bias
#pragma unroll
    for (int i = 0; i < 8; ++i) {
        int m = bm + ty * 8 + i;
        int b = m >> 11, t = m & (T_ - 1);
#pragma unroll
        for (int j = 0; j < 8; ++j) {
            int n = bn + tx * 8 + j;
            float val = acc[i][j] + bias[n];
            int sel = n >> 10, rem = n & 1023;
            int h = rem >> 6, d = rem & 63;
            float* dst = (sel == 0) ? qo : ((sel == 1) ? ko : vo);
            dst[((((size_t)b * H_ + h) * T_) + t) * D_ + d] = val;
        }
    }
}

// ---------------------------------------------------------------------------
// Attention: one wave per query row. lane = d (D=64 = wave width).
// Online softmax, causal. Writes output in-place over the q buffer.
// ---------------------------------------------------------------------------
__global__ __launch_bounds__(256) void attn_kernel(
    const float* __restrict__ q, const float* __restrict__ k,
    const float* __restrict__ v, float* __restrict__ o)
{
    const int wid = blockIdx.x * 4 + (threadIdx.x >> 6);
    const int lane = threadIdx.x & 63;
    const int r = wid & (T_ - 1);
    const int bh = wid >> 11;

    const float* kb = k + (size_t)bh * T_ * D_;
    const float* vb = v + (size_t)bh * T_ * D_;
    const float qd = q[((size_t)bh * T_ + r) * D_ + lane];

    float m = -INFINITY, l = 0.f, acc = 0.f;
    int j = 0;
    for (; j + 1 <= r; j += 2) {
        float s0 = qd * kb[j * D_ + lane];
        float s1 = qd * kb[(j + 1) * D_ + lane];
#pragma unroll
        for (int off = 32; off; off >>= 1) {
            s0 += __shfl_xor(s0, off, 64);
            s1 += __shfl_xor(s1, off, 64);
        }
        s0 *= 0.125f; s1 *= 0.125f;
        float mn = fmaxf(m, fmaxf(s0, s1));
        float scale = __expf(m - mn);
        float p0 = __expf(s0 - mn);
        float p1 = __expf(s1 - mn);
        l = l * scale + p0 + p1;
        acc = acc * scale + p0 * vb[j * D_ + lane] + p1 * vb[(j + 1) * D_ + lane];
        m = mn;
    }
    if (j <= r) {
        float s = qd * kb[j * D_ + lane];
#pragma unroll
        for (int off = 32; off; off >>= 1) s += __shfl_xor(s, off, 64);
        s *= 0.125f;
        float mn = fmaxf(m, s);
        float scale = __expf(m - mn);
        float p = __expf(s - mn);
        l = l * scale + p;
        acc = acc * scale + p * vb[j * D_ + lane];
        m = mn;
    }
    o[((size_t)bh * T_ + r) * D_ + lane] = acc / l;
}

// ---------------------------------------------------------------------------
// GEMM2: out = att @ w_out + b_out. A is read from [B,H,T,D] head layout.
// ---------------------------------------------------------------------------
__global__ __launch_bounds__(256) void gemm_out(
    const float* __restrict__ att,  // [B,H,T,D] layout
    const float* __restrict__ Bw,   // w_out [1024,1024]
    const float* __restrict__ bias, // [1024]
    float* __restrict__ out)        // [8192,1024]
{
    const int K = C_, N = C_;
    __shared__ __align__(16) float As[16][132];
    __shared__ __align__(16) float Bs[16][132];
    const int tid = threadIdx.x;
    const int bm = blockIdx.y * 128, bn = blockIdx.x * 128;
    const int ty = tid >> 4, tx = tid & 15;

    float acc[8][8];
#pragma unroll
    for (int i = 0; i < 8; ++i)
#pragma unroll
        for (int j = 0; j < 8; ++j) acc[i][j] = 0.f;

    for (int k0 = 0; k0 < K; k0 += 16) {
#pragma unroll
        for (int i = 0; i < 2; ++i) {
            int f = tid + 256 * i;
            int r = f >> 2, cc = (f & 3) << 2;
            int m = bm + r;
            int b = m >> 11, t = m & (T_ - 1);
            int c = k0 + cc;           // global K index
            int h = c >> 6, d = c & 63;
            float4 av = *reinterpret_cast<const float4*>(
                &att[((((size_t)b * H_ + h) * T_) + t) * D_ + d]);
            As[cc + 0][r] = av.x; As[cc + 1][r] = av.y;
            As[cc + 2][r] = av.z; As[cc + 3][r] = av.w;
        }
#pragma unroll
        for (int i = 0; i < 2; ++i) {
            int f = tid + 256 * i;
            int r = f >> 5, c = (f & 31) << 2;
            float4 bv = *reinterpret_cast<const float4*>(&Bw[(size_t)(k0 + r) * N + bn + c]);
            Bs[r][c + 0] = bv.x; Bs[r][c + 1] = bv.y;
            Bs[r][c + 2] = bv.z; Bs[r][c + 3] = bv.w;
        }
        __syncthreads();
#pragma unroll
        for (int kk = 0; kk < 16; ++kk) {
            float a[8], b[8];
#pragma unroll
            for (int i = 0; i < 8; i += 4) {
                float4 t = *reinterpret_cast<const float4*>(&As[kk][ty * 8 + i]);
                a[i] = t.x; a[i + 1] = t.y; a[i + 2] = t.z; a[i + 3] = t.w;
            }
#pragma unroll
            for (int j = 0; j < 8; j += 4) {
                float4 t = *reinterpret_cast<const float4*>(&Bs[kk][tx * 8 + j]);
                b[j] = t.x; b[j + 1] = t.y; b[j + 2] = t.z; b[j + 3] = t.w;
            }
#pragma unroll
            for (int i = 0; i < 8; ++i)
#pragma unroll
                for (int j = 0; j < 8; ++j)
                    acc[i][j] = fmaf(a[i], b[j], acc[i][j]);
        }
        __syncthreads();
    }

#pragma unroll
    for (int i = 0; i < 8; ++i) {
        int m = bm + ty * 8 + i;
#pragma unroll
        for (int j = 0; j < 8; ++j) {
            int n = bn + tx * 8 + j;
            out[(size_t)m * N + n] = acc[i][j] + bias[n];
        }
    }
}

// ---------------------------------------------------------------------------
extern "C" void kernel_launch(void* const* d_in, const int* in_sizes, int n_in,
                              void* d_out, int out_size, void* d_ws, size_t ws_size,
                              hipStream_t stream) {
    const float* x     = (const float*)d_in[0];
    const float* w_qkv = (const float*)d_in[1];
    const float* b_qkv = (const float*)d_in[2];
    const float* w_out = (const float*)d_in[3];
    const float* b_out = (const float*)d_in[4];
    float* out = (float*)d_out;

    const size_t per = (size_t)B_ * H_ * T_ * D_; // 8M floats = 32 MB
    float* qws = (float*)d_ws;
    float* kws = qws + per;
    float* vws = kws + per;

    dim3 g1(3 * C_ / 128, (B_ * T_) / 128); // (24, 64)
    gemm_qkv<<<g1, 256, 0, stream>>>(x, w_qkv, b_qkv, qws, kws, vws);

    dim3 ga((B_ * H_ * T_) / 4); // 32768 blocks, 4 waves each
    attn_kernel<<<ga, 256, 0, stream>>>(qws, kws, vws, qws);

    dim3 g2(C_ / 128, (B_ * T_) / 128); // (8, 64)
    gemm_out<<<g2, 256, 0, stream>>>(qws, w_out, b_out, out);
}

// Round 9
// 452.729 us; speedup vs baseline: 21.2997x; 21.2997x over previous
//
#include <hip/hip_runtime.h>
#include <math.h>

#define B_ 4
#define T_ 2048
#define C_ 1024
#define H_ 16
#define D_ 64
// M=8192, K=1024, N1=3072, N2=1024

typedef __attribute__((ext_vector_type(8))) short bf16x8;
typedef __attribute__((ext_vector_type(4))) float f32x4;

__device__ inline ushort f2bf(float f) {
    union { float f; unsigned u; } v; v.f = f;
    unsigned u = v.u;
    return (ushort)((u + 0x7FFFu + ((u >> 16) & 1u)) >> 16);
}

// --------------------------- x fp32 -> bf16 --------------------------------
__global__ __launch_bounds__(256) void convert_x(
    const float* __restrict__ in, ushort* __restrict__ out, int n8)
{
    int i = blockIdx.x * 256 + threadIdx.x;
    if (i >= n8) return;
    float4 a = *reinterpret_cast<const float4*>(&in[i * 8]);
    float4 b = *reinterpret_cast<const float4*>(&in[i * 8 + 4]);
    ushort o[8] = { f2bf(a.x), f2bf(a.y), f2bf(a.z), f2bf(a.w),
                    f2bf(b.x), f2bf(b.y), f2bf(b.z), f2bf(b.w) };
    *reinterpret_cast<bf16x8*>(&out[i * 8]) = *reinterpret_cast<bf16x8*>(o);
}

// ------------------ W fp32 [K,N] -> bf16 W^T [N,K] -------------------------
__global__ __launch_bounds__(256) void transpose_w(
    const float* __restrict__ in, ushort* __restrict__ out, int K, int N)
{
    __shared__ float tile[32][33];
    int k0 = blockIdx.y * 32, n0 = blockIdx.x * 32;
    int tr = threadIdx.x >> 3, tc = (threadIdx.x & 7) * 4;
    float4 v = *reinterpret_cast<const float4*>(&in[(size_t)(k0 + tr) * N + n0 + tc]);
    tile[tr][tc + 0] = v.x; tile[tr][tc + 1] = v.y;
    tile[tr][tc + 2] = v.z; tile[tr][tc + 3] = v.w;
    __syncthreads();
    ushort o[4];
#pragma unroll
    for (int i = 0; i < 4; ++i) o[i] = f2bf(tile[tc + i][tr]);
    *reinterpret_cast<ushort2*>(&out[(size_t)(n0 + tr) * K + k0 + tc]) =
        *reinterpret_cast<ushort2*>(&o[0]);
    *reinterpret_cast<ushort2*>(&out[(size_t)(n0 + tr) * K + k0 + tc + 2]) =
        *reinterpret_cast<ushort2*>(&o[2]);
}

// ---------------- bf16 MFMA GEMM: C = A[M,K] * Bt[N,K]^T -------------------
// 128x128 tile, BK=32, 4 waves (2x2 of 64x64), 16x16x32 MFMA.
#define APAD 40
__device__ inline void gemm_core(
    const ushort* __restrict__ Abase, const ushort* __restrict__ Bt,
    int K, int bm, int bn, ushort (*As)[APAD], ushort (*Bs)[APAD],
    f32x4 acc[4][4], int a_is_headlayout)
{
    const int tid = threadIdx.x;
    const int wid = tid >> 6, lane = tid & 63;
    const int lr = lane & 15, lg = lane >> 4;
    const int wr = wid >> 1, wc = wid & 1;

    for (int k0 = 0; k0 < K; k0 += 32) {
        __syncthreads();
#pragma unroll
        for (int i = 0; i < 2; ++i) {
            int f = tid + 256 * i;
            int r = f >> 2, c = (f & 3) * 8;
            const ushort* src;
            if (a_is_headlayout) {
                int m = bm + r, b = m >> 11, t = m & (T_ - 1);
                int kk = k0 + c, h = kk >> 6, d = kk & 63;
                src = &Abase[((((size_t)b * H_ + h) * T_) + t) * D_ + d];
            } else {
                src = &Abase[(size_t)(bm + r) * K + k0 + c];
            }
            *reinterpret_cast<bf16x8*>(&As[r][c]) =
                *reinterpret_cast<const bf16x8*>(src);
        }
#pragma unroll
        for (int i = 0; i < 2; ++i) {
            int f = tid + 256 * i;
            int r = f >> 2, c = (f & 3) * 8;
            *reinterpret_cast<bf16x8*>(&Bs[r][c]) =
                *reinterpret_cast<const bf16x8*>(&Bt[(size_t)(bn + r) * K + k0 + c]);
        }
        __syncthreads();

        bf16x8 a[4], b[4];
#pragma unroll
        for (int i = 0; i < 4; ++i) {
            a[i] = *reinterpret_cast<const bf16x8*>(&As[wr * 64 + i * 16 + lr][lg * 8]);
            b[i] = *reinterpret_cast<const bf16x8*>(&Bs[wc * 64 + i * 16 + lr][lg * 8]);
        }
#pragma unroll
        for (int i = 0; i < 4; ++i)
#pragma unroll
            for (int j = 0; j < 4; ++j)
                acc[i][j] = __builtin_amdgcn_mfma_f32_16x16x32_bf16(a[i], b[j], acc[i][j], 0, 0, 0);
    }
}

__global__ __launch_bounds__(256) void gemm1_mfma(
    const ushort* __restrict__ A,   // x bf16 [8192,1024]
    const ushort* __restrict__ Bt,  // w_qkv^T bf16 [3072,1024]
    const float* __restrict__ bias,
    ushort* __restrict__ qo, ushort* __restrict__ ko, ushort* __restrict__ vo)
{
    __shared__ ushort As[128][APAD];
    __shared__ ushort Bs[128][APAD];
    const int bm = blockIdx.y * 128, bn = blockIdx.x * 128;
    const int lane = threadIdx.x & 63, wid = threadIdx.x >> 6;
    const int lr = lane & 15, lg = lane >> 4;
    const int wr = wid >> 1, wc = wid & 1;
    f32x4 acc[4][4];
#pragma unroll
    for (int i = 0; i < 4; ++i)
#pragma unroll
        for (int j = 0; j < 4; ++j) acc[i][j] = (f32x4)(0.f);

    gemm_core(A, Bt, C_, bm, bn, As, Bs, acc, 0);

#pragma unroll
    for (int i = 0; i < 4; ++i)
#pragma unroll
        for (int r = 0; r < 4; ++r) {
            int m = bm + wr * 64 + i * 16 + lg * 4 + r;
            int b = m >> 11, t = m & (T_ - 1);
#pragma unroll
            for (int j = 0; j < 4; ++j) {
                int n = bn + wc * 64 + j * 16 + lr;
                float val = acc[i][j][r] + bias[n];
                int sel = n >> 10, rem = n & 1023;
                int h = rem >> 6, d = rem & 63;
                size_t bh = (size_t)b * H_ + h;
                if (sel == 0)      qo[(bh * T_ + t) * D_ + d] = f2bf(val * 0.125f);
                else if (sel == 1) ko[(bh * T_ + t) * D_ + d] = f2bf(val);
                else               vo[(bh * D_ + d) * T_ + t] = f2bf(val);
            }
        }
}

__global__ __launch_bounds__(256) void gemm2_mfma(
    const ushort* __restrict__ A,   // attn out bf16 [B*H,T,D] head layout
    const ushort* __restrict__ Bt,  // w_out^T bf16 [1024,1024]
    const float* __restrict__ bias,
    float* __restrict__ out)        // [8192,1024] fp32
{
    __shared__ ushort As[128][APAD];
    __shared__ ushort Bs[128][APAD];
    const int bm = blockIdx.y * 128, bn = blockIdx.x * 128;
    const int lane = threadIdx.x & 63, wid = threadIdx.x >> 6;
    const int lr = lane & 15, lg = lane >> 4;
    const int wr = wid >> 1, wc = wid & 1;
    f32x4 acc[4][4];
#pragma unroll
    for (int i = 0; i < 4; ++i)
#pragma unroll
        for (int j = 0; j < 4; ++j) acc[i][j] = (f32x4)(0.f);

    gemm_core(A, Bt, C_, bm, bn, As, Bs, acc, 1);

#pragma unroll
    for (int i = 0; i < 4; ++i)
#pragma unroll
        for (int r = 0; r < 4; ++r) {
            int m = bm + wr * 64 + i * 16 + lg * 4 + r;
#pragma unroll
            for (int j = 0; j < 4; ++j) {
                int n = bn + wc * 64 + j * 16 + lr;
                out[(size_t)m * C_ + n] = acc[i][j][r] + bias[n];
            }
        }
}

// ------------------------- flash attention ---------------------------------
#define KPAD 72
#define PPAD 68
__global__ __launch_bounds__(256) void attn_mfma(
    const ushort* __restrict__ q, const ushort* __restrict__ k,
    const ushort* __restrict__ vt, ushort* __restrict__ o)  // bf16 out
{
    __shared__ ushort Ks[64][KPAD];
    __shared__ ushort Vs[64][KPAD];
    __shared__ ushort Ps[4][16][PPAD];
    const int tid = threadIdx.x;
    const int wid = tid >> 6, lane = tid & 63;
    const int bh = blockIdx.y;
    const int q0 = blockIdx.x * 64;
    const int qw = q0 + wid * 16;
    const int lr = lane & 15, lg = lane >> 4;
    const ushort* qb = q + (size_t)bh * T_ * D_;
    const ushort* kb = k + (size_t)bh * T_ * D_;
    const ushort* vb = vt + (size_t)bh * D_ * T_;

    bf16x8 qf[2];
    qf[0] = *reinterpret_cast<const bf16x8*>(&qb[(size_t)(qw + lr) * D_ + lg * 8]);
    qf[1] = *reinterpret_cast<const bf16x8*>(&qb[(size_t)(qw + lr) * D_ + 32 + lg * 8]);

    f32x4 acc[4];
#pragma unroll
    for (int i = 0; i < 4; ++i) acc[i] = (f32x4)(0.f);
    float m[4], l[4];
#pragma unroll
    for (int r = 0; r < 4; ++r) { m[r] = -INFINITY; l[r] = 0.f; }

    const int ntiles = q0 / 64 + 1;
    for (int t = 0; t < ntiles; ++t) {
        const int kv0 = t * 64;
        __syncthreads();
#pragma unroll
        for (int i = 0; i < 2; ++i) {
            int c = tid + 256 * i;
            int row = c >> 3, col = (c & 7) * 8;
            *reinterpret_cast<bf16x8*>(&Ks[row][col]) =
                *reinterpret_cast<const bf16x8*>(&kb[(size_t)(kv0 + row) * D_ + col]);
        }
#pragma unroll
        for (int i = 0; i < 2; ++i) {
            int c = tid + 256 * i;
            int d = c >> 3, col = (c & 7) * 8;
            *reinterpret_cast<bf16x8*>(&Vs[d][col]) =
                *reinterpret_cast<const bf16x8*>(&vb[(size_t)d * T_ + kv0 + col]);
        }
        __syncthreads();

        f32x4 sv[4];
#pragma unroll
        for (int sub = 0; sub < 4; ++sub) {
            f32x4 c = (f32x4)(0.f);
            bf16x8 b0 = *reinterpret_cast<const bf16x8*>(&Ks[sub * 16 + lr][lg * 8]);
            bf16x8 b1 = *reinterpret_cast<const bf16x8*>(&Ks[sub * 16 + lr][32 + lg * 8]);
            c = __builtin_amdgcn_mfma_f32_16x16x32_bf16(qf[0], b0, c, 0, 0, 0);
            c = __builtin_amdgcn_mfma_f32_16x16x32_bf16(qf[1], b1, c, 0, 0, 0);
            sv[sub] = c;
        }
        if (t == ntiles - 1) {
#pragma unroll
            for (int sub = 0; sub < 4; ++sub)
#pragma unroll
                for (int r = 0; r < 4; ++r)
                    if (sub * 16 + lr > wid * 16 + lg * 4 + r) sv[sub][r] = -INFINITY;
        }
        float rescale[4];
#pragma unroll
        for (int r = 0; r < 4; ++r) {
            float v0 = fmaxf(fmaxf(sv[0][r], sv[1][r]), fmaxf(sv[2][r], sv[3][r]));
            v0 = fmaxf(v0, __shfl_xor(v0, 1));
            v0 = fmaxf(v0, __shfl_xor(v0, 2));
            v0 = fmaxf(v0, __shfl_xor(v0, 4));
            v0 = fmaxf(v0, __shfl_xor(v0, 8));
            float mn = fmaxf(m[r], v0);
            rescale[r] = __expf(m[r] - mn);
            m[r] = mn;
            l[r] *= rescale[r];
        }
#pragma unroll
        for (int ds = 0; ds < 4; ++ds)
#pragma unroll
            for (int r = 0; r < 4; ++r) acc[ds][r] *= rescale[r];
#pragma unroll
        for (int sub = 0; sub < 4; ++sub)
#pragma unroll
            for (int r = 0; r < 4; ++r)
                sv[sub][r] = __expf(sv[sub][r] - m[r]);
#pragma unroll
        for (int r = 0; r < 4; ++r) {
            float s = sv[0][r] + sv[1][r] + sv[2][r] + sv[3][r];
            s += __shfl_xor(s, 1);
            s += __shfl_xor(s, 2);
            s += __shfl_xor(s, 4);
            s += __shfl_xor(s, 8);
            l[r] += s;
        }
#pragma unroll
        for (int sub = 0; sub < 4; ++sub)
#pragma unroll
            for (int r = 0; r < 4; ++r)
                Ps[wid][lg * 4 + r][sub * 16 + lr] = f2bf(sv[sub][r]);
#pragma unroll
        for (int kc = 0; kc < 2; ++kc) {
            bf16x8 pa = *reinterpret_cast<const bf16x8*>(&Ps[wid][lr][kc * 32 + lg * 8]);
#pragma unroll
            for (int ds = 0; ds < 4; ++ds) {
                bf16x8 vv = *reinterpret_cast<const bf16x8*>(&Vs[ds * 16 + lr][kc * 32 + lg * 8]);
                acc[ds] = __builtin_amdgcn_mfma_f32_16x16x32_bf16(pa, vv, acc[ds], 0, 0, 0);
            }
        }
    }
    ushort* ob = o + (size_t)bh * T_ * D_;
#pragma unroll
    for (int r = 0; r < 4; ++r) {
        float inv = 1.f / l[r];
        int row = qw + lg * 4 + r;
#pragma unroll
        for (int ds = 0; ds < 4; ++ds)
            ob[(size_t)row * D_ + ds * 16 + lr] = f2bf(acc[ds][r] * inv);
    }
}

// ---------------------------------------------------------------------------
extern "C" void kernel_launch(void* const* d_in, const int* in_sizes, int n_in,
                              void* d_out, int out_size, void* d_ws, size_t ws_size,
                              hipStream_t stream) {
    const float* x     = (const float*)d_in[0];
    const float* w_qkv = (const float*)d_in[1];
    const float* b_qkv = (const float*)d_in[2];
    const float* w_out = (const float*)d_in[3];
    const float* b_out = (const float*)d_in[4];
    float* out = (float*)d_out;

    const size_t per = (size_t)B_ * H_ * T_ * D_;  // 8M
    ushort* qws   = (ushort*)d_ws;          // 16MB
    ushort* kws   = qws + per;              // 16MB
    ushort* vtws  = kws + per;              // 16MB
    ushort* ows   = vtws + per;             // attn out bf16, 16MB
    ushort* xbf   = ows + per;              // x bf16, 16MB
    ushort* wqkvT = xbf + per;              // 3072*1024 bf16, 6MB
    ushort* woutT = wqkvT + (size_t)3 * C_ * C_; // 1024*1024 bf16, 2MB

    convert_x<<<(B_ * T_ * C_ / 8 + 255) / 256, 256, 0, stream>>>(x, xbf, B_ * T_ * C_ / 8);
    transpose_w<<<dim3(3 * C_ / 32, C_ / 32), 256, 0, stream>>>(w_qkv, wqkvT, C_, 3 * C_);
    transpose_w<<<dim3(C_ / 32, C_ / 32), 256, 0, stream>>>(w_out, woutT, C_, C_);

    dim3 g1(3 * C_ / 128, (B_ * T_) / 128);
    gemm1_mfma<<<g1, 256, 0, stream>>>(xbf, wqkvT, b_qkv, qws, kws, vtws);

    dim3 ga(T_ / 64, B_ * H_);
    attn_mfma<<<ga, 256, 0, stream>>>(qws, kws, vtws, ows);

    dim3 g2(C_ / 128, (B_ * T_) / 128);
    gemm2_mfma<<<g2, 256, 0, stream>>>(ows, woutT, b_out, out);
}

// Round 10
// 356.009 us; speedup vs baseline: 27.0864x; 1.2717x over previous
//
#include <hip/hip_runtime.h>
#include <math.h>

#define B_ 4
#define T_ 2048
#define C_ 1024
#define H_ 16
#define D_ 64
// M=8192, K=1024, N1=3072, N2=1024

typedef __attribute__((ext_vector_type(8))) short bf16x8;
typedef __attribute__((ext_vector_type(4))) float f32x4;

__device__ inline ushort f2bf(float f) {
    union { float f; unsigned u; } v; v.f = f;
    unsigned u = v.u;
    return (ushort)((u + 0x7FFFu + ((u >> 16) & 1u)) >> 16);
}

// --------------------------- x fp32 -> bf16 --------------------------------
__global__ __launch_bounds__(256) void convert_x(
    const float* __restrict__ in, ushort* __restrict__ out, int n8)
{
    int i = blockIdx.x * 256 + threadIdx.x;
    if (i >= n8) return;
    float4 a = *reinterpret_cast<const float4*>(&in[i * 8]);
    float4 b = *reinterpret_cast<const float4*>(&in[i * 8 + 4]);
    ushort o[8] = { f2bf(a.x), f2bf(a.y), f2bf(a.z), f2bf(a.w),
                    f2bf(b.x), f2bf(b.y), f2bf(b.z), f2bf(b.w) };
    *reinterpret_cast<bf16x8*>(&out[i * 8]) = *reinterpret_cast<bf16x8*>(o);
}

// ------------------ W fp32 [K,N] -> bf16 W^T [N,K] -------------------------
__global__ __launch_bounds__(256) void transpose_w(
    const float* __restrict__ in, ushort* __restrict__ out, int K, int N)
{
    __shared__ float tile[32][33];
    int k0 = blockIdx.y * 32, n0 = blockIdx.x * 32;
    int tr = threadIdx.x >> 3, tc = (threadIdx.x & 7) * 4;
    float4 v = *reinterpret_cast<const float4*>(&in[(size_t)(k0 + tr) * N + n0 + tc]);
    tile[tr][tc + 0] = v.x; tile[tr][tc + 1] = v.y;
    tile[tr][tc + 2] = v.z; tile[tr][tc + 3] = v.w;
    __syncthreads();
    ushort o[4];
#pragma unroll
    for (int i = 0; i < 4; ++i) o[i] = f2bf(tile[tc + i][tr]);
    *reinterpret_cast<ushort2*>(&out[(size_t)(n0 + tr) * K + k0 + tc]) =
        *reinterpret_cast<ushort2*>(&o[0]);
    *reinterpret_cast<ushort2*>(&out[(size_t)(n0 + tr) * K + k0 + tc + 2]) =
        *reinterpret_cast<ushort2*>(&o[2]);
}

// ---------------- bf16 MFMA GEMM: C = A[M,K] * Bt[N,K]^T -------------------
// 128x128 tile, BK=32, 4 waves (2x2 of 64x64), 16x16x32 MFMA.
#define APAD 40
__device__ inline void gemm_core(
    const ushort* __restrict__ Abase, const ushort* __restrict__ Bt,
    int K, int bm, int bn, ushort (*As)[APAD], ushort (*Bs)[APAD],
    f32x4 acc[4][4], int a_is_headlayout)
{
    const int tid = threadIdx.x;
    const int wid = tid >> 6, lane = tid & 63;
    const int lr = lane & 15, lg = lane >> 4;
    const int wr = wid >> 1, wc = wid & 1;

    for (int k0 = 0; k0 < K; k0 += 32) {
        __syncthreads();
#pragma unroll
        for (int i = 0; i < 2; ++i) {
            int f = tid + 256 * i;
            int r = f >> 2, c = (f & 3) * 8;
            const ushort* src;
            if (a_is_headlayout) {
                int m = bm + r, b = m >> 11, t = m & (T_ - 1);
                int kk = k0 + c, h = kk >> 6, d = kk & 63;
                src = &Abase[((((size_t)b * H_ + h) * T_) + t) * D_ + d];
            } else {
                src = &Abase[(size_t)(bm + r) * K + k0 + c];
            }
            *reinterpret_cast<bf16x8*>(&As[r][c]) =
                *reinterpret_cast<const bf16x8*>(src);
        }
#pragma unroll
        for (int i = 0; i < 2; ++i) {
            int f = tid + 256 * i;
            int r = f >> 2, c = (f & 3) * 8;
            *reinterpret_cast<bf16x8*>(&Bs[r][c]) =
                *reinterpret_cast<const bf16x8*>(&Bt[(size_t)(bn + r) * K + k0 + c]);
        }
        __syncthreads();

        bf16x8 a[4], b[4];
#pragma unroll
        for (int i = 0; i < 4; ++i) {
            a[i] = *reinterpret_cast<const bf16x8*>(&As[wr * 64 + i * 16 + lr][lg * 8]);
            b[i] = *reinterpret_cast<const bf16x8*>(&Bs[wc * 64 + i * 16 + lr][lg * 8]);
        }
#pragma unroll
        for (int i = 0; i < 4; ++i)
#pragma unroll
            for (int j = 0; j < 4; ++j)
                acc[i][j] = __builtin_amdgcn_mfma_f32_16x16x32_bf16(a[i], b[j], acc[i][j], 0, 0, 0);
    }
}

__global__ __launch_bounds__(256) void gemm1_mfma(
    const ushort* __restrict__ A,   // x bf16 [8192,1024]
    const ushort* __restrict__ Bt,  // w_qkv^T bf16 [3072,1024]
    const float* __restrict__ bias,
    ushort* __restrict__ qo, ushort* __restrict__ ko, ushort* __restrict__ vo)
{
    __shared__ ushort As[128][APAD];
    __shared__ ushort Bs[128][APAD];
    const int bm = blockIdx.y * 128, bn = blockIdx.x * 128;
    const int lane = threadIdx.x & 63, wid = threadIdx.x >> 6;
    const int lr = lane & 15, lg = lane >> 4;
    const int wr = wid >> 1, wc = wid & 1;
    f32x4 acc[4][4];
#pragma unroll
    for (int i = 0; i < 4; ++i)
#pragma unroll
        for (int j = 0; j < 4; ++j) acc[i][j] = (f32x4)(0.f);

    gemm_core(A, Bt, C_, bm, bn, As, Bs, acc, 0);

#pragma unroll
    for (int i = 0; i < 4; ++i)
#pragma unroll
        for (int r = 0; r < 4; ++r) {
            int m = bm + wr * 64 + i * 16 + lg * 4 + r;
            int b = m >> 11, t = m & (T_ - 1);
#pragma unroll
            for (int j = 0; j < 4; ++j) {
                int n = bn + wc * 64 + j * 16 + lr;
                float val = acc[i][j][r] + bias[n];
                int sel = n >> 10, rem = n & 1023;
                int h = rem >> 6, d = rem & 63;
                size_t bh = (size_t)b * H_ + h;
                if (sel == 0)      qo[(bh * T_ + t) * D_ + d] = f2bf(val * 0.125f);
                else if (sel == 1) ko[(bh * T_ + t) * D_ + d] = f2bf(val);
                else               vo[(bh * D_ + d) * T_ + t] = f2bf(val);
            }
        }
}

__global__ __launch_bounds__(256) void gemm2_mfma(
    const ushort* __restrict__ A,   // attn out bf16 [B*H,T,D] head layout
    const ushort* __restrict__ Bt,  // w_out^T bf16 [1024,1024]
    const float* __restrict__ bias,
    float* __restrict__ out)        // [8192,1024] fp32
{
    __shared__ ushort As[128][APAD];
    __shared__ ushort Bs[128][APAD];
    const int bm = blockIdx.y * 128, bn = blockIdx.x * 128;
    const int lane = threadIdx.x & 63, wid = threadIdx.x >> 6;
    const int lr = lane & 15, lg = lane >> 4;
    const int wr = wid >> 1, wc = wid & 1;
    f32x4 acc[4][4];
#pragma unroll
    for (int i = 0; i < 4; ++i)
#pragma unroll
        for (int j = 0; j < 4; ++j) acc[i][j] = (f32x4)(0.f);

    gemm_core(A, Bt, C_, bm, bn, As, Bs, acc, 1);

#pragma unroll
    for (int i = 0; i < 4; ++i)
#pragma unroll
        for (int r = 0; r < 4; ++r) {
            int m = bm + wr * 64 + i * 16 + lg * 4 + r;
#pragma unroll
            for (int j = 0; j < 4; ++j) {
                int n = bn + wc * 64 + j * 16 + lr;
                out[(size_t)m * C_ + n] = acc[i][j][r] + bias[n];
            }
        }
}

// ------------------------- flash attention ---------------------------------
// Causal load-balance: block x processes q-tiles {x, 31-x} -> 33 KV-tiles/block.
#define KPAD 72
#define PPAD 68
#define NT_ (T_ / 64)   // 32 q-tiles
__global__ __launch_bounds__(256) void attn_mfma(
    const ushort* __restrict__ q, const ushort* __restrict__ k,
    const ushort* __restrict__ vt, ushort* __restrict__ o)  // bf16 out
{
    __shared__ ushort Ks[64][KPAD];
    __shared__ ushort Vs[64][KPAD];
    __shared__ ushort Ps[4][16][PPAD];
    const int tid = threadIdx.x;
    const int wid = tid >> 6, lane = tid & 63;
    const int bh = blockIdx.y;
    const int lr = lane & 15, lg = lane >> 4;
    const ushort* qb = q + (size_t)bh * T_ * D_;
    const ushort* kb = k + (size_t)bh * T_ * D_;
    const ushort* vb = vt + (size_t)bh * D_ * T_;
    ushort* ob = o + (size_t)bh * T_ * D_;

    for (int half = 0; half < 2; ++half) {
        const int qt = half == 0 ? (int)blockIdx.x : (NT_ - 1 - (int)blockIdx.x);
        const int q0 = qt * 64;
        const int qw = q0 + wid * 16;

        bf16x8 qf[2];
        qf[0] = *reinterpret_cast<const bf16x8*>(&qb[(size_t)(qw + lr) * D_ + lg * 8]);
        qf[1] = *reinterpret_cast<const bf16x8*>(&qb[(size_t)(qw + lr) * D_ + 32 + lg * 8]);

        f32x4 acc[4];
#pragma unroll
        for (int i = 0; i < 4; ++i) acc[i] = (f32x4)(0.f);
        float m[4], l[4];
#pragma unroll
        for (int r = 0; r < 4; ++r) { m[r] = -INFINITY; l[r] = 0.f; }

        const int ntiles = qt + 1;
        for (int t = 0; t < ntiles; ++t) {
            const int kv0 = t * 64;
            __syncthreads();  // protect K/V/P LDS from previous iteration's readers
#pragma unroll
            for (int i = 0; i < 2; ++i) {
                int c = tid + 256 * i;
                int row = c >> 3, col = (c & 7) * 8;
                *reinterpret_cast<bf16x8*>(&Ks[row][col]) =
                    *reinterpret_cast<const bf16x8*>(&kb[(size_t)(kv0 + row) * D_ + col]);
            }
#pragma unroll
            for (int i = 0; i < 2; ++i) {
                int c = tid + 256 * i;
                int d = c >> 3, col = (c & 7) * 8;
                *reinterpret_cast<bf16x8*>(&Vs[d][col]) =
                    *reinterpret_cast<const bf16x8*>(&vb[(size_t)d * T_ + kv0 + col]);
            }
            __syncthreads();

            f32x4 sv[4];
#pragma unroll
            for (int sub = 0; sub < 4; ++sub) {
                f32x4 c = (f32x4)(0.f);
                bf16x8 b0 = *reinterpret_cast<const bf16x8*>(&Ks[sub * 16 + lr][lg * 8]);
                bf16x8 b1 = *reinterpret_cast<const bf16x8*>(&Ks[sub * 16 + lr][32 + lg * 8]);
                c = __builtin_amdgcn_mfma_f32_16x16x32_bf16(qf[0], b0, c, 0, 0, 0);
                c = __builtin_amdgcn_mfma_f32_16x16x32_bf16(qf[1], b1, c, 0, 0, 0);
                sv[sub] = c;
            }
            if (t == ntiles - 1) {
#pragma unroll
                for (int sub = 0; sub < 4; ++sub)
#pragma unroll
                    for (int r = 0; r < 4; ++r)
                        if (sub * 16 + lr > wid * 16 + lg * 4 + r) sv[sub][r] = -INFINITY;
            }
            float rescale[4];
#pragma unroll
            for (int r = 0; r < 4; ++r) {
                float v0 = fmaxf(fmaxf(sv[0][r], sv[1][r]), fmaxf(sv[2][r], sv[3][r]));
                v0 = fmaxf(v0, __shfl_xor(v0, 1));
                v0 = fmaxf(v0, __shfl_xor(v0, 2));
                v0 = fmaxf(v0, __shfl_xor(v0, 4));
                v0 = fmaxf(v0, __shfl_xor(v0, 8));
                float mn = fmaxf(m[r], v0);
                rescale[r] = __expf(m[r] - mn);
                m[r] = mn;
                l[r] *= rescale[r];
            }
#pragma unroll
            for (int ds = 0; ds < 4; ++ds)
#pragma unroll
                for (int r = 0; r < 4; ++r) acc[ds][r] *= rescale[r];
#pragma unroll
            for (int sub = 0; sub < 4; ++sub)
#pragma unroll
                for (int r = 0; r < 4; ++r)
                    sv[sub][r] = __expf(sv[sub][r] - m[r]);
#pragma unroll
            for (int r = 0; r < 4; ++r) {
                float s = sv[0][r] + sv[1][r] + sv[2][r] + sv[3][r];
                s += __shfl_xor(s, 1);
                s += __shfl_xor(s, 2);
                s += __shfl_xor(s, 4);
                s += __shfl_xor(s, 8);
                l[r] += s;
            }
#pragma unroll
            for (int sub = 0; sub < 4; ++sub)
#pragma unroll
                for (int r = 0; r < 4; ++r)
                    Ps[wid][lg * 4 + r][sub * 16 + lr] = f2bf(sv[sub][r]);
#pragma unroll
            for (int kc = 0; kc < 2; ++kc) {
                bf16x8 pa = *reinterpret_cast<const bf16x8*>(&Ps[wid][lr][kc * 32 + lg * 8]);
#pragma unroll
                for (int ds = 0; ds < 4; ++ds) {
                    bf16x8 vv = *reinterpret_cast<const bf16x8*>(&Vs[ds * 16 + lr][kc * 32 + lg * 8]);
                    acc[ds] = __builtin_amdgcn_mfma_f32_16x16x32_bf16(pa, vv, acc[ds], 0, 0, 0);
                }
            }
        }

#pragma unroll
        for (int r = 0; r < 4; ++r) {
            float inv = 1.f / l[r];
            int row = qw + lg * 4 + r;
#pragma unroll
            for (int ds = 0; ds < 4; ++ds)
                ob[(size_t)row * D_ + ds * 16 + lr] = f2bf(acc[ds][r] * inv);
        }
    }
}

// ---------------------------------------------------------------------------
extern "C" void kernel_launch(void* const* d_in, const int* in_sizes, int n_in,
                              void* d_out, int out_size, void* d_ws, size_t ws_size,
                              hipStream_t stream) {
    const float* x     = (const float*)d_in[0];
    const float* w_qkv = (const float*)d_in[1];
    const float* b_qkv = (const float*)d_in[2];
    const float* w_out = (const float*)d_in[3];
    const float* b_out = (const float*)d_in[4];
    float* out = (float*)d_out;

    const size_t per = (size_t)B_ * H_ * T_ * D_;  // 8M
    ushort* qws   = (ushort*)d_ws;          // 16MB
    ushort* kws   = qws + per;              // 16MB
    ushort* vtws  = kws + per;              // 16MB
    ushort* ows   = vtws + per;             // attn out bf16, 16MB
    ushort* xbf   = ows + per;              // x bf16, 16MB
    ushort* wqkvT = xbf + per;              // 3072*1024 bf16, 6MB
    ushort* woutT = wqkvT + (size_t)3 * C_ * C_; // 1024*1024 bf16, 2MB

    convert_x<<<(B_ * T_ * C_ / 8 + 255) / 256, 256, 0, stream>>>(x, xbf, B_ * T_ * C_ / 8);
    transpose_w<<<dim3(3 * C_ / 32, C_ / 32), 256, 0, stream>>>(w_qkv, wqkvT, C_, 3 * C_);
    transpose_w<<<dim3(C_ / 32, C_ / 32), 256, 0, stream>>>(w_out, woutT, C_, C_);

    dim3 g1(3 * C_ / 128, (B_ * T_) / 128);
    gemm1_mfma<<<g1, 256, 0, stream>>>(xbf, wqkvT, b_qkv, qws, kws, vtws);

    dim3 ga(T_ / 128, B_ * H_);  // (16, 64): paired q-tiles, 33 KV-tiles/block
    attn_mfma<<<ga, 256, 0, stream>>>(qws, kws, vtws, ows);

    dim3 g2(C_ / 128, (B_ * T_) / 128);
    gemm2_mfma<<<g2, 256, 0, stream>>>(ows, woutT, b_out, out);
}